// Round 13
// baseline (660.586 us; speedup 1.0000x reference)
//
#include <hip/hip_runtime.h>
#include <cstdint>
#include <cstddef>

// ---------------- types / helpers ----------------
typedef __bf16 bf16x8 __attribute__((ext_vector_type(8)));
typedef float f32x4 __attribute__((ext_vector_type(4)));

__device__ __forceinline__ unsigned short f2bf(float f) {
  unsigned u = __float_as_uint(f);
  u += 0x7fffu + ((u >> 16) & 1u);   // RNE
  return (unsigned short)(u >> 16);
}
__device__ __forceinline__ float bf2f(unsigned short s) {
  return __uint_as_float(((unsigned)s) << 16);
}

// async global->LDS, 16B per lane, linear dest (wave-uniform base + lane*16)
__device__ __forceinline__ void gld_lds16(const void* g, void* l) {
  __builtin_amdgcn_global_load_lds(
      (const __attribute__((address_space(1))) void*)g,
      (__attribute__((address_space(3))) void*)l, 16, 0, 0);
}

#define BARM() do { __builtin_amdgcn_s_barrier(); asm volatile("" ::: "memory"); } while (0)
#define VMCNT(n) asm volatile("s_waitcnt vmcnt(" #n ")" ::: "memory")
// lgkmcnt(0) WITHOUT sched_barrier: certifies this wave's ds_reads complete
// before the following BARM (asm-asm ordering); MFMAs remain free to float.
#define LGKMW() asm volatile("s_waitcnt lgkmcnt(0)" ::: "memory")

// ---------------- transpose + convert W [K][N] f32 -> Wt [N][K] bf16 ----------------
__global__ void transpose_w(const float* __restrict__ w, unsigned short* __restrict__ wt,
                            int K, int N) {
  __shared__ float tile[32][33];
  int nt = N >> 5;
  int bx = blockIdx.x % nt;   // n tile
  int by = blockIdx.x / nt;   // k tile
  int tx = threadIdx.x & 31, ty = threadIdx.x >> 5;  // 32x8
#pragma unroll
  for (int r = 0; r < 32; r += 8)
    tile[ty + r][tx] = w[(size_t)(by * 32 + ty + r) * N + bx * 32 + tx];
  __syncthreads();
#pragma unroll
  for (int r = 0; r < 32; r += 8)
    wt[(size_t)(bx * 32 + ty + r) * K + by * 32 + tx] = f2bf(tile[tx][ty + r]);
}

// ---------------- x f32 -> bf16 (chunk, zero-pad rows >= nvalid) ----------------
__global__ void cvt_x(const float* __restrict__ x, unsigned short* __restrict__ xb,
                      int rows, int nvalid, int D) {
  size_t total = (size_t)rows * D / 8;
  for (size_t i = (size_t)blockIdx.x * blockDim.x + threadIdx.x; i < total;
       i += (size_t)gridDim.x * blockDim.x) {
    size_t e = i * 8;
    int row = (int)(e / (size_t)D);
    uint4 ov;
    if (row < nvalid) {
      const float4* s = (const float4*)(x + e);
      float4 v0 = s[0], v1 = s[1];
      ov.x = (unsigned)f2bf(v0.x) | ((unsigned)f2bf(v0.y) << 16);
      ov.y = (unsigned)f2bf(v0.z) | ((unsigned)f2bf(v0.w) << 16);
      ov.z = (unsigned)f2bf(v1.x) | ((unsigned)f2bf(v1.y) << 16);
      ov.w = (unsigned)f2bf(v1.z) | ((unsigned)f2bf(v1.w) << 16);
    } else {
      ov.x = ov.y = ov.z = ov.w = 0u;
    }
    *(uint4*)(xb + e) = ov;
  }
}

// ---------------- 256x256 GEMM, 16 waves, 1-barrier/K64 free-slip schedule ----------------
// Round-13 change vs r12: remove the mid-tile barrier entirely. Per tile t
// (slot s=t&1): issue all 4 stages for t+1 -> s^1 up front, then each wave
// independently {read k0 frags; MFMA; read k1 frags; MFMA}; LGKMW; VMCNT(0);
// BAR. Waves slip by up to a full tile, so one wave's MFMA burst covers
// another's LDS read burst (the r12 wall: read/MFMA phases serialized by the
// mid-tile rendezvous).
// Race proof:
//  (1) stage target is s^1 only; its last readers (tile t-1) were certified by
//      the t-1 end-barrier, which each wave passed only after its LGKMW
//      covered those reads. Nothing reads s^1 during tile t.
//  (2) staged-data-ready: the 4 gld_lds for t+1 are issued at tile-t start
//      and waited a full tile (~5000 cyc) later -> VMCNT(0) is a stall-free
//      drain of old loads; the following BAR makes it collective.
//  (3) ds_read/gld_lds are memory ops: cannot cross BARM's memory clobber;
//      MFMAs (reg-only) float freely — their operand waits are compiler-
//      inserted fine-grained lgkmcnt.
__device__ __forceinline__ bf16x8 read_frag(const unsigned short* region, int row, int kel) {
  int ke = kel ^ (((row >> 1) & 3) << 3);
  return *(const bf16x8*)(region + row * 32 + ke);
}

__device__ __forceinline__ void stage_half(const unsigned short* gpanel, int K, int kofs,
                                           unsigned short* region, int tid) {
  int row = tid >> 2;                                  // 1024 threads -> 256 rows x 4
  int ke = ((tid & 3) * 8) ^ (((row >> 1) & 3) << 3);  // inverse-swizzled source
  gld_lds16(gpanel + (size_t)row * K + kofs + ke, region + tid * 8);
}

#define MFMA16X(BV)                                                             \
  _Pragma("unroll") for (int mm = 0; mm < 4; ++mm)                              \
      _Pragma("unroll") for (int nn = 0; nn < 4; ++nn)                          \
          acc[mm][nn] = __builtin_amdgcn_mfma_f32_16x16x32_bf16(                \
              av[mm], BV[nn], acc[mm][nn], 0, 0, 0)

// Shared K-loop body. Defines acc[4][4]; caller provides epilogue.
#define GEMM_PREAMBLE_AND_KLOOP()                                               \
  const int tid = threadIdx.x;                                                  \
  const int w = tid >> 6, l = tid & 63;                                         \
  const int wm = w >> 2, wn = w & 3;                                            \
  const int lc = l & 15, lk8 = (l >> 4) * 8;                                    \
  const int nbn = N >> 8;                                                       \
  const int nwg = gridDim.x;                                                    \
  const int q = nwg >> 3, rr = nwg & 7;                                         \
  const int xcd = blockIdx.x & 7, ib = blockIdx.x >> 3;                         \
  const int bswz = (xcd < rr ? xcd * (q + 1) : rr * (q + 1) + (xcd - rr) * q) + ib; \
  const int bm = bswz / nbn, bn = bswz - bm * nbn;                              \
  const unsigned short* Ap = A + (size_t)bm * 256 * K;                          \
  const unsigned short* Bp = Bt + (size_t)bn * 256 * K;                         \
  const int T = K >> 6;                                                         \
  f32x4 acc[4][4] = {};                                                         \
  stage_half(Ap, K, 0, &lds[0][0][0][0][0], tid);                               \
  stage_half(Bp, K, 0, &lds[0][1][0][0][0], tid);                               \
  stage_half(Ap, K, 32, &lds[0][0][1][0][0], tid);                              \
  stage_half(Bp, K, 32, &lds[0][1][1][0][0], tid);                              \
  VMCNT(0);                                                                     \
  BARM();                                                                       \
  for (int t = 0; t < T; ++t) {                                                 \
    const int s = t & 1;                                                        \
    const unsigned short* Ak0 = &lds[s][0][0][0][0];                            \
    const unsigned short* Ak1 = &lds[s][0][1][0][0];                            \
    const unsigned short* Bk0 = &lds[s][1][0][0][0];                            \
    const unsigned short* Bk1 = &lds[s][1][1][0][0];                            \
    unsigned short* nAk0 = &lds[s ^ 1][0][0][0][0];                             \
    unsigned short* nBk0 = &lds[s ^ 1][1][0][0][0];                             \
    unsigned short* nAk1 = &lds[s ^ 1][0][1][0][0];                             \
    unsigned short* nBk1 = &lds[s ^ 1][1][1][0][0];                             \
    bf16x8 av[4], bq[4];                                                        \
    if (t + 1 < T) {                                                            \
      stage_half(Ap, K, (t + 1) * 64, nAk0, tid);                               \
      stage_half(Bp, K, (t + 1) * 64, nBk0, tid);                               \
      stage_half(Ap, K, (t + 1) * 64 + 32, nAk1, tid);                          \
      stage_half(Bp, K, (t + 1) * 64 + 32, nBk1, tid);                          \
    }                                                                           \
    /* ---- half 0 (k0) ---- */                                                 \
    _Pragma("unroll") for (int mm = 0; mm < 4; ++mm)                            \
        av[mm] = read_frag(Ak0, wm * 64 + mm * 16 + lc, lk8);                   \
    _Pragma("unroll") for (int nn = 0; nn < 4; ++nn)                            \
        bq[nn] = read_frag(Bk0, wn * 64 + nn * 16 + lc, lk8);                   \
    MFMA16X(bq);                                                                \
    /* ---- half 1 (k1) ---- */                                                 \
    _Pragma("unroll") for (int mm = 0; mm < 4; ++mm)                            \
        av[mm] = read_frag(Ak1, wm * 64 + mm * 16 + lc, lk8);                   \
    _Pragma("unroll") for (int nn = 0; nn < 4; ++nn)                            \
        bq[nn] = read_frag(Bk1, wn * 64 + nn * 16 + lc, lk8);                   \
    MFMA16X(bq);                                                                \
    LGKMW();          /* this wave's slot-s reads complete */                   \
    VMCNT(0);         /* t+1 staged data landed (issued a full tile ago) */     \
    BARM();           /* collective: slot handoff certified */                  \
  }

__global__ __launch_bounds__(1024, 1) void gemm256(
    const unsigned short* __restrict__ A,   // [M][K] bf16
    const unsigned short* __restrict__ Bt,  // [N][K] bf16
    const float* __restrict__ bias,         // [N] f32
    unsigned short* __restrict__ C,         // [M][N] bf16
    int N, int K) {
  __shared__ alignas(16) unsigned short lds[2][2][2][256][32];   // 128 KiB
  GEMM_PREAMBLE_AND_KLOOP();

  // ---- epilogue: acc -> LDS (row-XOR swizzle) -> coalesced dwordx4 stores ----
  unsigned short* eps = &lds[0][0][0][0][0];   // [128][256] bf16 per round
  float bv[4];
#pragma unroll
  for (int nn = 0; nn < 4; ++nn) bv[nn] = bias[bn * 256 + wn * 64 + nn * 16 + lc];

#pragma unroll
  for (int r = 0; r < 2; ++r) {
    if ((wm >> 1) == r) {                      // waves wm=2r,2r+1 own rows r*128..+127
#pragma unroll
      for (int mm = 0; mm < 4; ++mm) {
#pragma unroll
        for (int nn = 0; nn < 4; ++nn) {
          int lcol = wn * 64 + nn * 16 + lc;
#pragma unroll
          for (int j = 0; j < 4; ++j) {
            int lrow = (wm & 1) * 64 + mm * 16 + (l >> 4) * 4 + j;
            float v = fmaxf(acc[mm][nn][j] + bv[nn], 0.0f);
            eps[lrow * 256 + (lcol ^ (((lrow >> 2) & 3) << 4))] = f2bf(v);
          }
        }
      }
    }
    BARM();
#pragma unroll
    for (int it = 0; it < 4; ++it) {
      int flat = it * 1024 + tid;          // 4096 = 128 rows x 32 col-granules
      int lrow = flat >> 5, cb = flat & 31;
      int ce = (cb * 8) ^ (((lrow >> 2) & 3) << 4);
      uint4 v = *(const uint4*)&eps[lrow * 256 + ce];
      *(uint4*)&C[(size_t)(bm * 256 + r * 128 + lrow) * N + bn * 256 + cb * 8] = v;
    }
    BARM();
  }
}

// Last layer: identical K-loop; segment-sum relu'd outputs per graph via
// atomicAdd into part[G][N] (batch sorted; pad rows -> sentinel -1).
__global__ __launch_bounds__(1024, 1) void gemm_pool(
    const unsigned short* __restrict__ A,   // [M][K] bf16 (chunk base)
    const unsigned short* __restrict__ Bt,  // [N][K] bf16
    const float* __restrict__ bias,         // [N] f32
    const int* __restrict__ batch,          // [Nn] sorted graph ids (global)
    float* __restrict__ part,               // [G][N] f32 accumulators
    int N, int K, int row0, int Nn) {       // row0 = chunk offset in global rows
  __shared__ alignas(16) unsigned short lds[2][2][2][256][32];   // 128 KiB
  GEMM_PREAMBLE_AND_KLOOP();

  unsigned short* eps = &lds[0][0][0][0][0];
  int* batchLS = (int*)&lds[1][0][0][0][0];   // slot 1 is free post-loop
  if (tid < 256) {
    int grow = row0 + bm * 256 + tid;
    batchLS[tid] = (grow < Nn) ? batch[grow] : -1;
  }
  float bv[4];
#pragma unroll
  for (int nn = 0; nn < 4; ++nn) bv[nn] = bias[bn * 256 + wn * 64 + nn * 16 + lc];

#pragma unroll
  for (int r = 0; r < 2; ++r) {
    if ((wm >> 1) == r) {
#pragma unroll
      for (int mm = 0; mm < 4; ++mm) {
#pragma unroll
        for (int nn = 0; nn < 4; ++nn) {
          int lcol = wn * 64 + nn * 16 + lc;
#pragma unroll
          for (int j = 0; j < 4; ++j) {
            int lrow = (wm & 1) * 64 + mm * 16 + (l >> 4) * 4 + j;
            float v = fmaxf(acc[mm][nn][j] + bv[nn], 0.0f);
            eps[lrow * 256 + (lcol ^ (((lrow >> 2) & 3) << 4))] = f2bf(v);
          }
        }
      }
    }
    BARM();
    // column scan: thread -> (col = tid&255, rows qt*32..qt*32+31)
    {
      int col = tid & 255;
      int qt = tid >> 8;                   // 0..3
      int gcur = -2;
      float run = 0.f;
      int gcolbase = bn * 256 + col;
      for (int i = 0; i < 32; ++i) {
        int lr = qt * 32 + i;
        int g = batchLS[r * 128 + lr];
        if (g != gcur) {
          if (gcur >= 0) atomicAdd(&part[(size_t)gcur * N + gcolbase], run);
          gcur = g; run = 0.f;
        }
        run += bf2f(eps[lr * 256 + (col ^ (((lr >> 2) & 3) << 4))]);
      }
      if (gcur >= 0) atomicAdd(&part[(size_t)gcur * N + gcolbase], run);
    }
    BARM();
  }
}

// ---------------- pool finalize ----------------
__global__ void zero_part(float* __restrict__ part, int n) {
  int i = blockIdx.x * blockDim.x + threadIdx.x;
  if (i < n) part[i] = 0.f;
}

__global__ void pool_div(const float* __restrict__ part, const int* __restrict__ batch,
                         float* __restrict__ out, int n, int D, int G) {
  int idx = blockIdx.x * blockDim.x + threadIdx.x;
  if (idx >= G * D) return;
  int g = idx / D;
  int lo, hi;
  { int a = 0, b = n; while (a < b) { int m = (a + b) >> 1; if (batch[m] < g) a = m + 1; else b = m; } lo = a; }
  { int a = lo, b = n; while (a < b) { int m = (a + b) >> 1; if (batch[m] < g + 1) a = m + 1; else b = m; } hi = a; }
  out[idx] = part[idx] / (float)(hi - lo);
}

// ---------------- launcher ----------------
static inline size_t align256(size_t x) { return (x + 255) & ~(size_t)255; }

extern "C" void kernel_launch(void* const* d_in, const int* in_sizes, int n_in,
                              void* d_out, int out_size, void* d_ws, size_t ws_size,
                              hipStream_t stream) {
  const float* x = (const float*)d_in[0];
  // d_in[1] = edge_index (unused by the math)
  const int* batch = (const int*)d_in[2];
  const float* W0 = (const float*)d_in[3];
  const float* b0 = (const float*)d_in[4];
  const float* W1 = (const float*)d_in[5];
  const float* b1 = (const float*)d_in[6];
  const float* W2 = (const float*)d_in[7];
  const float* b2 = (const float*)d_in[8];
  float* out = (float*)d_out;

  const int Nn = in_sizes[2];                 // 100000 nodes
  const int DIN = 512, DH = 1024, DOUT = 512;
  const int G = out_size / DOUT;              // 128
  const int Mpad = ((Nn + 255) / 256) * 256;  // 100096

  // workspace layout (h2 eliminated)
  uint8_t* p = (uint8_t*)d_ws;
  unsigned short* W0t = (unsigned short*)p; p += align256((size_t)DH * DIN * 2);
  unsigned short* W1t = (unsigned short*)p; p += align256((size_t)DH * DH * 2);
  unsigned short* W2t = (unsigned short*)p; p += align256((size_t)DOUT * DH * 2);
  float* part         = (float*)p;          p += align256((size_t)G * DOUT * 4);
  size_t used = (size_t)(p - (uint8_t*)d_ws);
  size_t avail = ws_size > used ? ws_size - used : 0;
  size_t per_row = (size_t)(DIN + DH + DH) * 2;       // xb + h0 + h1 bytes per row
  long long chl = (long long)(avail / per_row);
  chl = (chl / 256) * 256;
  int CH = (int)(chl < 256 ? 256 : chl);
  if (CH > Mpad) CH = Mpad;
  unsigned short* xb = (unsigned short*)p; p += align256((size_t)CH * DIN * 2);
  unsigned short* h0 = (unsigned short*)p; p += align256((size_t)CH * DH * 2);
  unsigned short* h1 = (unsigned short*)p; p += align256((size_t)CH * DH * 2);

  // 0) zero the pooling accumulators
  zero_part<<<dim3((G * DOUT + 255) / 256), 256, 0, stream>>>(part, G * DOUT);

  // 1) weights: transpose + convert to bf16 [N][K]
  transpose_w<<<dim3((DIN / 32) * (DH / 32)), 256, 0, stream>>>(W0, W0t, DIN, DH);
  transpose_w<<<dim3((DH / 32) * (DH / 32)), 256, 0, stream>>>(W1, W1t, DH, DH);
  transpose_w<<<dim3((DH / 32) * (DOUT / 32)), 256, 0, stream>>>(W2, W2t, DH, DOUT);

  // 2) chunked 3-layer MLP (single chunk when ws allows); L2 fuses the pool
  for (int off = 0; off < Mpad; off += CH) {
    int rows = Mpad - off; if (rows > CH) rows = CH;
    int nvalid = Nn - off;
    size_t cvt_threads = (size_t)rows * DIN / 8;
    int cvt_blocks = (int)((cvt_threads + 255) / 256);
    if (cvt_blocks > 2048) cvt_blocks = 2048;
    cvt_x<<<dim3(cvt_blocks), 256, 0, stream>>>(x + (size_t)off * DIN, xb, rows, nvalid, DIN);

    gemm256<<<dim3((rows / 256) * (DH / 256)), 1024, 0, stream>>>(xb, W0t, b0, h0, DH, DIN);
    gemm256<<<dim3((rows / 256) * (DH / 256)), 1024, 0, stream>>>(h0, W1t, b1, h1, DH, DH);
    gemm_pool<<<dim3((rows / 256) * (DOUT / 256)), 1024, 0, stream>>>(
        h1, W2t, b2, batch, part, DOUT, DH, off, Nn);
  }

  // 3) finalize: mean = sum / count
  pool_div<<<dim3((G * DOUT + 255) / 256), 256, 0, stream>>>(part, batch, out, Nn, DOUT, G);
}